// Round 9
// baseline (1365.023 us; speedup 1.0000x reference)
//
#include <hip/hip_runtime.h>
#include <hip/hip_bf16.h>
#include <math.h>

// Problem constants (match reference)
#define NFEAT 512
#define NHID  64
#define NHEADS 8
#define HD    512   // NHEADS*NHID
#define NOUT  64

typedef _Float16 half8 __attribute__((ext_vector_type(8)));
typedef _Float16 half4 __attribute__((ext_vector_type(4)));
typedef float floatx4 __attribute__((ext_vector_type(4)));

// ---------------------------------------------------------------------------
// Kernel 1: fold attention vectors through fW:  G[16][512], C16[16]
// ---------------------------------------------------------------------------
__global__ void g_k(const float* __restrict__ fW_w, const float* __restrict__ fW_b,
                    const float* __restrict__ a_src, const float* __restrict__ a_dest,
                    float* __restrict__ G, float* __restrict__ C16)
{
    int idx = blockIdx.x * blockDim.x + threadIdx.x;
    if (idx < 16 * 512) {
        int r = idx >> 9;       // 0..15
        int f = idx & 511;
        int h = r & 7;
        const float* a = (r < 8) ? a_src : a_dest;
        float s = 0.f;
        #pragma unroll 8
        for (int d = 0; d < 64; ++d)
            s = fmaf(fW_w[(size_t)(h * 64 + d) * 512 + f], a[h * 64 + d], s);
        G[(size_t)r * 512 + f] = s;
    } else if (idx < 16 * 512 + 16) {
        int r = idx - 16 * 512;
        int h = r & 7;
        const float* a = (r < 8) ? a_src : a_dest;
        float s = 0.f;
        for (int d = 0; d < 64; ++d)
            s = fmaf(fW_b[h * 64 + d], a[h * 64 + d], s);
        C16[r] = s;
    }
}

// ---------------------------------------------------------------------------
// Kernel 2: skinny GEMM [N,512] x G^T -> f1[N,8], f2[N,8]; fused feat->fp16.
// ---------------------------------------------------------------------------
#define FB_BM 128
#define FB_BK 64
__global__ __launch_bounds__(256) void f1f2_k(const float* __restrict__ feat,
    const float* __restrict__ G, const float* __restrict__ C16,
    float* __restrict__ f1, float* __restrict__ f2,
    _Float16* __restrict__ featH, int M)
{
    __shared__ float As[FB_BK][FB_BM + 4];
    __shared__ float Gs[16][FB_BK + 1];
    int tid = threadIdx.x;
    int tx = tid & 15;          // output column 0..15
    int ty = tid >> 4;          // 0..15
    int m0 = blockIdx.x * FB_BM;
    float acc[8] = {0.f, 0.f, 0.f, 0.f, 0.f, 0.f, 0.f, 0.f};

    for (int k0 = 0; k0 < NFEAT; k0 += FB_BK) {
        __syncthreads();
        #pragma unroll
        for (int j = 0; j < 8; ++j) {
            int fid = tid + 256 * j;       // 0..2047 float4 slots
            int ml = fid >> 4;             // row 0..127
            int k4 = fid & 15;             // float4 within k-tile
            float4 v = make_float4(0.f, 0.f, 0.f, 0.f);
            int gm = m0 + ml;
            if (gm < M) {
                v = *(const float4*)(feat + (size_t)gm * NFEAT + k0 + k4 * 4);
                half4 hv;
                hv[0] = (_Float16)v.x; hv[1] = (_Float16)v.y;
                hv[2] = (_Float16)v.z; hv[3] = (_Float16)v.w;
                *(half4*)(featH + (size_t)gm * NFEAT + k0 + k4 * 4) = hv;
            }
            As[k4 * 4 + 0][ml] = v.x;
            As[k4 * 4 + 1][ml] = v.y;
            As[k4 * 4 + 2][ml] = v.z;
            As[k4 * 4 + 3][ml] = v.w;
        }
        {
            int gr = tid >> 4;             // 0..15
            int k4 = tid & 15;
            float4 v = *(const float4*)(G + (size_t)gr * 512 + k0 + k4 * 4);
            Gs[gr][k4 * 4 + 0] = v.x;
            Gs[gr][k4 * 4 + 1] = v.y;
            Gs[gr][k4 * 4 + 2] = v.z;
            Gs[gr][k4 * 4 + 3] = v.w;
        }
        __syncthreads();
        #pragma unroll 16
        for (int kk = 0; kk < FB_BK; ++kk) {
            float g = Gs[tx][kk];
            #pragma unroll
            for (int i = 0; i < 8; ++i)
                acc[i] = fmaf(As[kk][ty + 16 * i], g, acc[i]);
        }
    }
    float c = C16[tx];
    #pragma unroll
    for (int i = 0; i < 8; ++i) {
        int gm = m0 + ty + 16 * i;
        if (gm < M) {
            float v = acc[i] + c;
            if (tx < 8) f1[(size_t)gm * 8 + tx] = v;
            else        f2[(size_t)gm * 8 + (tx - 8)] = v;
        }
    }
}

// ---------------------------------------------------------------------------
// CSR build: zero, count, hierarchical scan, fill
// ---------------------------------------------------------------------------
__global__ void zero_k(int* __restrict__ deg, int* __restrict__ fill, int n)
{
    int i = blockIdx.x * blockDim.x + threadIdx.x;
    if (i < n) { deg[i] = 0; fill[i] = 0; }
}

__global__ void count_k(const int* __restrict__ ei, int* __restrict__ deg, int E)
{
    int e = blockIdx.x * blockDim.x + threadIdx.x;
    if (e < E) atomicAdd(&deg[ei[e]], 1);
}

__global__ __launch_bounds__(1024) void bscan_k(const int* __restrict__ deg,
    int* __restrict__ row_ptr, int* __restrict__ bsum, int n)
{
    __shared__ int sh[1024];
    int tid = threadIdx.x;
    int i = blockIdx.x * 1024 + tid;
    int x = (i < n) ? deg[i] : 0;
    sh[tid] = x;
    __syncthreads();
    for (int off = 1; off < 1024; off <<= 1) {
        int v = (tid >= off) ? sh[tid - off] : 0;
        __syncthreads();
        sh[tid] += v;
        __syncthreads();
    }
    if (i < n) row_ptr[i] = sh[tid] - x;    // exclusive within block
    if (tid == 1023) bsum[blockIdx.x] = sh[1023];
}

__global__ void sscan_k(int* __restrict__ bsum, int nb)
{
    if (blockIdx.x == 0 && threadIdx.x == 0) {
        int run = 0;
        for (int b = 0; b < nb; ++b) { int t = bsum[b]; bsum[b] = run; run += t; }
    }
}

__global__ void addoff_k(int* __restrict__ row_ptr, const int* __restrict__ bsum,
                         int n, int Etot)
{
    int i = blockIdx.x * blockDim.x + threadIdx.x;
    if (i < n) row_ptr[i] += bsum[i >> 10];
    if (i == 0) row_ptr[n] = Etot;
}

__global__ void fill_k(const int* __restrict__ ei, const int* __restrict__ row_ptr,
                       int* __restrict__ fill, int* __restrict__ col_s, int E)
{
    int e = blockIdx.x * blockDim.x + threadIdx.x;
    if (e >= E) return;
    int r = ei[e];
    int c = ei[E + e];
    int o = atomicAdd(&fill[r], 1);
    col_s[row_ptr[r] + o] = c;
}

// ---------------------------------------------------------------------------
// Attention: ONE THREAD PER ROW, all 8 heads in registers. col_s read once,
// f2 read as one coalesced 32B gather per edge, attn written [E][8] via two
// floatx4 NT stores (full-line). inv_den coalesced [N][8]. tr_k produces the
// [8][E] layout agg needs.
// ---------------------------------------------------------------------------
__global__ void attn_k(const int* __restrict__ row_ptr, const int* __restrict__ col_s,
                       const float* __restrict__ f1, const float* __restrict__ f2,
                       float* __restrict__ attn_e8, float* __restrict__ inv_den,
                       int n_rows)
{
    int n = blockIdx.x * blockDim.x + threadIdx.x;
    if (n >= n_rows) return;
    int s = row_ptr[n], epos = row_ptr[n + 1];
    floatx4 fa = *(const floatx4*)(f1 + (size_t)n * 8);
    floatx4 fb = *(const floatx4*)(f1 + (size_t)n * 8 + 4);
    float F1[8] = {fa[0], fa[1], fa[2], fa[3], fb[0], fb[1], fb[2], fb[3]};
    float den[8] = {0.f, 0.f, 0.f, 0.f, 0.f, 0.f, 0.f, 0.f};
    for (int p = s; p < epos; ++p) {
        int c = col_s[p];
        floatx4 ga = *(const floatx4*)(f2 + (size_t)c * 8);
        floatx4 gb = *(const floatx4*)(f2 + (size_t)c * 8 + 4);
        float F2[8] = {ga[0], ga[1], ga[2], ga[3], gb[0], gb[1], gb[2], gb[3]};
        float ex[8];
        #pragma unroll
        for (int h = 0; h < 8; ++h) {
            float t = F1[h] + F2[h];
            t = (t > 0.f) ? t : 0.2f * t;   // LeakyReLU
            ex[h] = expf(t);
            den[h] += ex[h];
        }
        floatx4 lo = {ex[0], ex[1], ex[2], ex[3]};
        floatx4 hi = {ex[4], ex[5], ex[6], ex[7]};
        __builtin_nontemporal_store(lo, (floatx4*)(attn_e8 + (size_t)p * 8));
        __builtin_nontemporal_store(hi, (floatx4*)(attn_e8 + (size_t)p * 8 + 4));
    }
    floatx4 iv0, iv1;
    #pragma unroll
    for (int h = 0; h < 4; ++h) iv0[h] = (den[h] > 0.f) ? 1.f / den[h] : 0.f;
    #pragma unroll
    for (int h = 0; h < 4; ++h) iv1[h] = (den[h + 4] > 0.f) ? 1.f / den[h + 4] : 0.f;
    *(floatx4*)(inv_den + (size_t)n * 8)     = iv0;
    *(floatx4*)(inv_den + (size_t)n * 8 + 4) = iv1;
}

// ---------------------------------------------------------------------------
// Transpose [E][8] -> [8][E]. Thread = edge: one 32B coalesced read, then for
// each head the wave's 64 lanes write 64 CONSECUTIVE e-slots = 256B of fully
// written contiguous lines. Clean 51+51MB streaming, NT stores.
// ---------------------------------------------------------------------------
__global__ void tr_k(const float* __restrict__ in, float* __restrict__ out, int E)
{
    int e = blockIdx.x * blockDim.x + threadIdx.x;
    if (e >= E) return;
    floatx4 a = *(const floatx4*)(in + (size_t)e * 8);
    floatx4 b = *(const floatx4*)(in + (size_t)e * 8 + 4);
    __builtin_nontemporal_store(a[0], out + 0 * (size_t)E + e);
    __builtin_nontemporal_store(a[1], out + 1 * (size_t)E + e);
    __builtin_nontemporal_store(a[2], out + 2 * (size_t)E + e);
    __builtin_nontemporal_store(a[3], out + 3 * (size_t)E + e);
    __builtin_nontemporal_store(b[0], out + 4 * (size_t)E + e);
    __builtin_nontemporal_store(b[1], out + 5 * (size_t)E + e);
    __builtin_nontemporal_store(b[2], out + 6 * (size_t)E + e);
    __builtin_nontemporal_store(b[3], out + 7 * (size_t)E + e);
}

// ---------------------------------------------------------------------------
// fp32 -> fp16 conversion (n multiple of 8)
// ---------------------------------------------------------------------------
__global__ void cvt_f16_k(const float* __restrict__ in, _Float16* __restrict__ out,
                          size_t n)
{
    size_t i = ((size_t)blockIdx.x * blockDim.x + threadIdx.x) * 8;
    if (i >= n) return;
    float4 a = *(const float4*)(in + i);
    float4 b = *(const float4*)(in + i + 4);
    half8 h;
    h[0] = (_Float16)a.x; h[1] = (_Float16)a.y; h[2] = (_Float16)a.z; h[3] = (_Float16)a.w;
    h[4] = (_Float16)b.x; h[5] = (_Float16)b.y; h[6] = (_Float16)b.z; h[7] = (_Float16)b.w;
    *(half8*)(out + i) = h;
}

// ---------------------------------------------------------------------------
// fp16 MFMA GEMM: A[M,K] * B[N,K]^T + bias -> C head-major [N/64][M][64].
// ONE BLOCK PER M-PANEL: internal nb-loop covers all N/TN n-blocks, so the
// 128KB A-panel is fetched once and re-served from the block's own L2.
// 128x128 tile, BK=64, global_load_lds width 16, T2 XOR swizzle via
// pre-swizzled global source. K%64==0, N%128==0.
// ---------------------------------------------------------------------------
#define TM 128
#define TN 128
#define TK 64
__global__ __launch_bounds__(256) void gemm_f16_mfma(
    const _Float16* __restrict__ A,   // [M,K]
    const _Float16* __restrict__ B,   // [N,K]
    const float* __restrict__ bias,   // [N]
    _Float16* __restrict__ C,         // [N/64][M][64] head-major
    int M, int N, int K)
{
    __shared__ _Float16 smem_h[TM * TK + TN * TK];   // 32 KB; reused for epilogue
    _Float16* Ash = smem_h;
    _Float16* Bsh = smem_h + TM * TK;
    int tid = threadIdx.x;
    int wave = tid >> 6;
    int lane = tid & 63;
    int m0 = blockIdx.x * TM;
    int wm = (wave & 1) * 64;
    int wn = (wave >> 1) * 64;

    int fm = lane & 15;
    int q  = lane >> 4;
    int lrow = lane >> 3;                 // 0..7: row within one load instr
    int lcol = (lane & 7) ^ lrow;         // pre-swizzled source col16 slot

    for (int nb = 0; nb < N / TN; ++nb) {
        int n0 = nb * TN;
        floatx4 acc[4][4] = {};

        for (int k0 = 0; k0 < K; k0 += TK) {
            __syncthreads();
            #pragma unroll
            for (int t = 0; t < 4; ++t) {
                int r = wave * 8 + t * 32;           // 8 rows per instr, 128 total
                int gr = m0 + r + lrow;
                if (gr > M - 1) gr = M - 1;
                const _Float16* ga = A + (size_t)gr * K + k0 + lcol * 8;
                __builtin_amdgcn_global_load_lds(
                    (const __attribute__((address_space(1))) void*)ga,
                    (__attribute__((address_space(3))) void*)&Ash[r * TK], 16, 0, 0);
                const _Float16* gb = B + (size_t)(n0 + r + lrow) * K + k0 + lcol * 8;
                __builtin_amdgcn_global_load_lds(
                    (const __attribute__((address_space(1))) void*)gb,
                    (__attribute__((address_space(3))) void*)&Bsh[r * TK], 16, 0, 0);
            }
            __syncthreads();
            #pragma unroll
            for (int kq = 0; kq < 2; ++kq) {
                half8 af[4], bf[4];
                int sw = ((kq << 2) + q);
                #pragma unroll
                for (int i = 0; i < 4; ++i) {
                    int ar = wm + i * 16 + fm;
                    af[i] = *(const half8*)&Ash[ar * TK + ((sw ^ (fm & 7)) << 3)];
                    int br = wn + i * 16 + fm;
                    bf[i] = *(const half8*)&Bsh[br * TK + ((sw ^ (fm & 7)) << 3)];
                }
                #pragma unroll
                for (int i = 0; i < 4; ++i)
                    #pragma unroll
                    for (int j = 0; j < 4; ++j)
                        acc[i][j] = __builtin_amdgcn_mfma_f32_16x16x32_f16(af[i], bf[j], acc[i][j], 0, 0, 0);
            }
        }
        // Epilogue: per i-subtile (16 rows x 64 cols per wave), stage in LDS
        // with rq-based XOR swizzle, read back coalesced, half8 store.
        // Each wave's 64-col chunk = exactly one head -> head-major store.
        int cn = lane & 15;
        int rq = lane >> 4;               // 0..3
        int head = (n0 + wn) >> 6;
        _Float16* Csh = smem_h + wave * 1024;   // 16*64 halves per wave
        #pragma unroll
        for (int i = 0; i < 4; ++i) {
            __syncthreads();              // protect smem reuse across waves/stages
            #pragma unroll
            for (int j = 0; j < 4; ++j) {
                int col = j * 16 + cn;                  // 0..63
                float bsv = bias[n0 + wn + col];
                int scol = col ^ (rq * 16);             // swizzle: rq picks 16-col block
                #pragma unroll
                for (int r = 0; r < 4; ++r) {
                    int row = rq * 4 + r;               // 0..15
                    Csh[row * 64 + scol] = (_Float16)(acc[i][j][r] + bsv);
                }
            }
            __syncthreads();
            #pragma unroll
            for (int t = 0; t < 2; ++t) {
                int row = t * 8 + (lane >> 3);          // 0..15
                int c0 = (lane & 7) * 8;                // aligned-8 col run
                int sc0 = c0 ^ (((row >> 2) & 3) * 16); // same swizzle (rq = row>>2)
                half8 v = *(const half8*)&Csh[row * 64 + sc0];
                int gm = m0 + wm + i * 16 + row;
                if (gm < M)
                    *(half8*)&C[((size_t)head * M + gm) * 64 + c0] = v;
            }
        }
    }
}

// ---------------------------------------------------------------------------
// fp16 MFMA GEMM, N=64, fp32 out: C[M,64] = A[M,K]*B[64,K]^T + bias
// ---------------------------------------------------------------------------
#define FG_TM 256
#define FG_TK 32
__global__ __launch_bounds__(256) void gemm_f16_n64(
    const _Float16* __restrict__ A,   // [M,K]
    const _Float16* __restrict__ B,   // [64,K]
    const float* __restrict__ bias,   // [64]
    float* __restrict__ C,            // [M,64]
    int M, int K)
{
    __shared__ _Float16 Ash[FG_TM * FG_TK];
    __shared__ _Float16 Bsh[64 * FG_TK];
    int tid = threadIdx.x;
    int wave = tid >> 6;
    int lane = tid & 63;
    int m0 = blockIdx.x * FG_TM;
    int wm = wave * 64;

    floatx4 acc[4][4] = {};
    int fm = lane & 15;
    int q  = lane >> 4;

    for (int k0 = 0; k0 < K; k0 += FG_TK) {
        __syncthreads();
        #pragma unroll
        for (int t = 0; t < 4; ++t) {
            int r = wave * 16 + t * 64;
            int gr = m0 + r + (lane >> 2);
            if (gr > M - 1) gr = M - 1;
            const _Float16* ga = A + (size_t)gr * K + k0 + (lane & 3) * 8;
            __builtin_amdgcn_global_load_lds(
                (const __attribute__((address_space(1))) void*)ga,
                (__attribute__((address_space(3))) void*)&Ash[r * FG_TK], 16, 0, 0);
        }
        {
            int r = wave * 16;
            const _Float16* gb = B + (size_t)(r + (lane >> 2)) * K + k0 + (lane & 3) * 8;
            __builtin_amdgcn_global_load_lds(
                (const __attribute__((address_space(1))) void*)gb,
                (__attribute__((address_space(3))) void*)&Bsh[r * FG_TK], 16, 0, 0);
        }
        __syncthreads();
        half8 af[4], bf[4];
        #pragma unroll
        for (int i = 0; i < 4; ++i) {
            af[i] = *(const half8*)&Ash[(wm + i * 16 + fm) * FG_TK + q * 8];
            bf[i] = *(const half8*)&Bsh[(i * 16 + fm) * FG_TK + q * 8];
        }
        #pragma unroll
        for (int i = 0; i < 4; ++i)
            #pragma unroll
            for (int j = 0; j < 4; ++j)
                acc[i][j] = __builtin_amdgcn_mfma_f32_16x16x32_f16(af[i], bf[j], acc[i][j], 0, 0, 0);
    }
    int cn = lane & 15;
    int rq = lane >> 4;
    #pragma unroll
    for (int i = 0; i < 4; ++i) {
        #pragma unroll
        for (int j = 0; j < 4; ++j) {
            int gn = j * 16 + cn;
            float bsv = bias[gn];
            #pragma unroll
            for (int r = 0; r < 4; ++r) {
                int gm = m0 + wm + i * 16 + rq * 4 + r;
                if (gm < M)
                    C[(size_t)gm * NOUT + gn] = acc[i][j][r] + bsv;
            }
        }
    }
}

// ---------------------------------------------------------------------------
// HEAD-PARTITIONED aggregation, 4-edge unroll. Round-8 diagnosis: agg is
// LATENCY x MLP bound, not BW bound (rate tracks occupancy x in-flight
// gathers: r0 48%x4 -> 3.93 TB/s, r8 81%x2 -> 3.75 TB/s). Four independent
// 16B gathers in flight per lane doubles outstanding bytes at retained
// occupancy (2 accumulator arrays keep VGPR ~= 46 <= 64; __launch_bounds__
// (256,8) pins 8 blocks/CU). head = bid%8 -> per-XCD 12.8MB gather table.
// ---------------------------------------------------------------------------
__global__ __launch_bounds__(256, 8) void agg_h_k(const int* __restrict__ row_ptr,
    const int* __restrict__ col_s, const float* __restrict__ attn_t,
    const float* __restrict__ inv_den, const _Float16* __restrict__ xw,
    _Float16* __restrict__ out, int n_rows, int E)
{
    int head   = blockIdx.x & 7;
    int rowblk = blockIdx.x >> 3;
    int wave   = threadIdx.x >> 6;
    int lane   = threadIdx.x & 63;
    int row    = rowblk * 32 + wave * 8 + (lane >> 3);
    int cs     = lane & 7;             // channel slot: 8 fp16 = 16B
    const float*    attn_h = attn_t + (size_t)head * E;
    const _Float16* xw_h   = xw + (size_t)head * n_rows * 64;

    bool act = row < n_rows;
    int s = act ? row_ptr[row]     : 0;
    int e = act ? row_ptr[row + 1] : 0;

    float acc0[8] = {0.f, 0.f, 0.f, 0.f, 0.f, 0.f, 0.f, 0.f};
    float acc1[8] = {0.f, 0.f, 0.f, 0.f, 0.f, 0.f, 0.f, 0.f};
    int p = s;
    for (; p + 4 <= e; p += 4) {
        int c0 = col_s[p];
        int c1 = col_s[p + 1];
        int c2 = col_s[p + 2];
        int c3 = col_s[p + 3];
        float a0 = attn_h[p];
        float a1 = attn_h[p + 1];
        float a2 = attn_h[p + 2];
        float a3 = attn_h[p + 3];
        half8 x0 = *(const half8*)(xw_h + (size_t)c0 * 64 + cs * 8);
        half8 x1 = *(const half8*)(xw_h + (size_t)c1 * 64 + cs * 8);
        half8 x2 = *(const half8*)(xw_h + (size_t)c2 * 64 + cs * 8);
        half8 x3 = *(const half8*)(xw_h + (size_t)c3 * 64 + cs * 8);
        #pragma unroll
        for (int u = 0; u < 8; ++u) {
            acc0[u] = fmaf(a0, (float)x0[u], acc0[u]);
            acc1[u] = fmaf(a1, (float)x1[u], acc1[u]);
        }
        #pragma unroll
        for (int u = 0; u < 8; ++u) {
            acc0[u] = fmaf(a2, (float)x2[u], acc0[u]);
            acc1[u] = fmaf(a3, (float)x3[u], acc1[u]);
        }
    }
    for (; p < e; ++p) {
        int c0 = col_s[p];
        float a0 = attn_h[p];
        half8 x0 = *(const half8*)(xw_h + (size_t)c0 * 64 + cs * 8);
        #pragma unroll
        for (int u = 0; u < 8; ++u)
            acc0[u] = fmaf(a0, (float)x0[u], acc0[u]);
    }
    if (!act) return;
    float inv = inv_den[(size_t)row * 8 + head];
    half8 o;
    #pragma unroll
    for (int u = 0; u < 8; ++u) {
        float v = (acc0[u] + acc1[u]) * inv;
        v = (v > 0.f) ? v : (expf(v) - 1.f);   // ELU
        o[u] = (_Float16)v;
    }
    __builtin_nontemporal_store(o,
        (half8*)(out + (size_t)row * HD + head * 64 + cs * 8));
}

// ---------------------------------------------------------------------------
extern "C" void kernel_launch(void* const* d_in, const int* in_sizes, int n_in,
                              void* d_out, int out_size, void* d_ws, size_t ws_size,
                              hipStream_t stream)
{
    const float* feat   = (const float*)d_in[0];
    const int*   ei     = (const int*)  d_in[1];
    const float* fW_w   = (const float*)d_in[2];
    const float* fW_b   = (const float*)d_in[3];
    const float* a_src  = (const float*)d_in[4];
    const float* a_dest = (const float*)d_in[5];
    const float* W0     = (const float*)d_in[6];
    const float* b0     = (const float*)d_in[7];
    const float* W1     = (const float*)d_in[8];
    const float* b1     = (const float*)d_in[9];
    const float* lin_w  = (const float*)d_in[10];
    const float* lin_b  = (const float*)d_in[11];
    float* outp = (float*)d_out;

    const int N = in_sizes[0] / NFEAT;
    const int E = in_sizes[1] / 2;
    const int NB = (N + 1023) / 1024;

    // workspace carve-up (256B aligned)
    char* ws = (char*)d_ws;
    size_t off = 0;
    auto carve = [&](size_t bytes) -> char* {
        char* p = ws + off;
        off += (bytes + 255) & ~(size_t)255;
        return p;
    };
    float*     G       = (float*)carve(16 * 512 * sizeof(float));
    float*     C16     = (float*)carve(16 * sizeof(float));
    float*     f1      = (float*)carve((size_t)N * 8 * sizeof(float));
    float*     f2      = (float*)carve((size_t)N * 8 * sizeof(float));
    int*       deg     = (int*)  carve((size_t)N * sizeof(int));
    int*       fillc   = (int*)  carve((size_t)N * sizeof(int));
    int*       row_ptr = (int*)  carve(((size_t)N + 1) * sizeof(int));
    int*       bsum    = (int*)  carve((size_t)NB * sizeof(int));
    int*       col_s   = (int*)  carve((size_t)E * sizeof(int));
    float*     attn_t  = (float*)carve((size_t)E * 8 * sizeof(float));   // [8][E]
    float*     inv_den = (float*)carve((size_t)N * 8 * sizeof(float));   // [N][8]
    _Float16*  W0h     = (_Float16*)carve((size_t)HD * NFEAT * sizeof(_Float16));
    _Float16*  W1h     = (_Float16*)carve((size_t)HD * HD * sizeof(_Float16));
    _Float16*  linWh   = (_Float16*)carve((size_t)NOUT * HD * sizeof(_Float16));
    _Float16*  hbuf1   = (_Float16*)carve((size_t)N * NFEAT * sizeof(_Float16)); // featH -> x1H -> x2H
    _Float16*  xwH     = (_Float16*)carve((size_t)N * HD * sizeof(_Float16));    // [8][N][64]
    // [E][8] attn scratch ALIASES xwH (dead until first GEMM; 102MB >= 51MB)
    float*     attn_e8 = (float*)xwH;
    (void)ws_size; (void)n_in; (void)out_size;

    // 1. fold a_src/a_dest through fW; f1/f2 per node (+ fused feat->fp16)
    g_k<<<(16 * 512 + 16 + 255) / 256, 256, 0, stream>>>(fW_w, fW_b, a_src, a_dest, G, C16);
    f1f2_k<<<(N + FB_BM - 1) / FB_BM, 256, 0, stream>>>(feat, G, C16, f1, f2, hbuf1, N);
    // 2. CSR build
    zero_k<<<(N + 255) / 256, 256, 0, stream>>>(deg, fillc, N);
    count_k<<<(E + 255) / 256, 256, 0, stream>>>(ei, deg, E);
    bscan_k<<<NB, 1024, 0, stream>>>(deg, row_ptr, bsum, N);
    sscan_k<<<1, 64, 0, stream>>>(bsum, NB);
    addoff_k<<<(N + 255) / 256, 256, 0, stream>>>(row_ptr, bsum, N, E);
    fill_k<<<(E + 255) / 256, 256, 0, stream>>>(ei, row_ptr, fillc, col_s, E);
    // 3. attention: per-row thread, [E][8] coalesced + inv [N][8]; then
    //    transpose to [8][E] for the head-partitioned agg.
    attn_k<<<(N + 255) / 256, 256, 0, stream>>>(row_ptr, col_s, f1, f2, attn_e8, inv_den, N);
    tr_k<<<(E + 255) / 256, 256, 0, stream>>>(attn_e8, attn_t, E);

    // 4. weight conversions to fp16
    cvt_f16_k<<<(int)(((size_t)HD * NFEAT / 8 + 255) / 256), 256, 0, stream>>>(W0, W0h, (size_t)HD * NFEAT);
    cvt_f16_k<<<(int)(((size_t)HD * HD / 8 + 255) / 256), 256, 0, stream>>>(W1, W1h, (size_t)HD * HD);
    cvt_f16_k<<<(int)(((size_t)NOUT * HD / 8 + 255) / 256), 256, 0, stream>>>(lin_w, linWh, (size_t)NOUT * HD);

    const int agg_blocks = 8 * ((N + 31) / 32);   // head = bid%8, 32 rows/block

    // 5. layer 0: xw0 = feat @ W0^T + b0 -> xwH (head-major); agg -> hbuf1
    gemm_f16_mfma<<<(N + TM - 1) / TM, 256, 0, stream>>>(
        hbuf1, W0h, b0, xwH, N, HD, NFEAT);
    agg_h_k<<<agg_blocks, 256, 0, stream>>>(
        row_ptr, col_s, attn_t, inv_den, xwH, hbuf1, N, E);
    // 6. layer 1: xw1 = x1 @ W1^T + b1 -> xwH (head-major); agg -> hbuf1
    gemm_f16_mfma<<<(N + TM - 1) / TM, 256, 0, stream>>>(
        hbuf1, W1h, b1, xwH, N, HD, HD);
    agg_h_k<<<agg_blocks, 256, 0, stream>>>(
        row_ptr, col_s, attn_t, inv_den, xwH, hbuf1, N, E);
    // 7. final linear (fp16 MFMA, fp32 out) -> d_out
    gemm_f16_n64<<<(N + FG_TM - 1) / FG_TM, 256, 0, stream>>>(
        hbuf1, linWh, lin_b, outp, N, HD);
}

// Round 10
// 1254.954 us; speedup vs baseline: 1.0877x; 1.0877x over previous
//
#include <hip/hip_runtime.h>
#include <hip/hip_bf16.h>
#include <math.h>

// Problem constants (match reference)
#define NFEAT 512
#define NHID  64
#define NHEADS 8
#define HD    512   // NHEADS*NHID
#define NOUT  64

typedef _Float16 half8 __attribute__((ext_vector_type(8)));
typedef _Float16 half4 __attribute__((ext_vector_type(4)));
typedef float floatx4 __attribute__((ext_vector_type(4)));

// ---------------------------------------------------------------------------
// Kernel 1: fold attention vectors through fW:  G[16][512], C16[16]
// ---------------------------------------------------------------------------
__global__ void g_k(const float* __restrict__ fW_w, const float* __restrict__ fW_b,
                    const float* __restrict__ a_src, const float* __restrict__ a_dest,
                    float* __restrict__ G, float* __restrict__ C16)
{
    int idx = blockIdx.x * blockDim.x + threadIdx.x;
    if (idx < 16 * 512) {
        int r = idx >> 9;       // 0..15
        int f = idx & 511;
        int h = r & 7;
        const float* a = (r < 8) ? a_src : a_dest;
        float s = 0.f;
        #pragma unroll 8
        for (int d = 0; d < 64; ++d)
            s = fmaf(fW_w[(size_t)(h * 64 + d) * 512 + f], a[h * 64 + d], s);
        G[(size_t)r * 512 + f] = s;
    } else if (idx < 16 * 512 + 16) {
        int r = idx - 16 * 512;
        int h = r & 7;
        const float* a = (r < 8) ? a_src : a_dest;
        float s = 0.f;
        for (int d = 0; d < 64; ++d)
            s = fmaf(fW_b[h * 64 + d], a[h * 64 + d], s);
        C16[r] = s;
    }
}

// ---------------------------------------------------------------------------
// Kernel 2: skinny GEMM [N,512] x G^T -> f1[N,8], f2[N,8]; fused feat->fp16.
// ---------------------------------------------------------------------------
#define FB_BM 128
#define FB_BK 64
__global__ __launch_bounds__(256) void f1f2_k(const float* __restrict__ feat,
    const float* __restrict__ G, const float* __restrict__ C16,
    float* __restrict__ f1, float* __restrict__ f2,
    _Float16* __restrict__ featH, int M)
{
    __shared__ float As[FB_BK][FB_BM + 4];
    __shared__ float Gs[16][FB_BK + 1];
    int tid = threadIdx.x;
    int tx = tid & 15;          // output column 0..15
    int ty = tid >> 4;          // 0..15
    int m0 = blockIdx.x * FB_BM;
    float acc[8] = {0.f, 0.f, 0.f, 0.f, 0.f, 0.f, 0.f, 0.f};

    for (int k0 = 0; k0 < NFEAT; k0 += FB_BK) {
        __syncthreads();
        #pragma unroll
        for (int j = 0; j < 8; ++j) {
            int fid = tid + 256 * j;       // 0..2047 float4 slots
            int ml = fid >> 4;             // row 0..127
            int k4 = fid & 15;             // float4 within k-tile
            float4 v = make_float4(0.f, 0.f, 0.f, 0.f);
            int gm = m0 + ml;
            if (gm < M) {
                v = *(const float4*)(feat + (size_t)gm * NFEAT + k0 + k4 * 4);
                half4 hv;
                hv[0] = (_Float16)v.x; hv[1] = (_Float16)v.y;
                hv[2] = (_Float16)v.z; hv[3] = (_Float16)v.w;
                *(half4*)(featH + (size_t)gm * NFEAT + k0 + k4 * 4) = hv;
            }
            As[k4 * 4 + 0][ml] = v.x;
            As[k4 * 4 + 1][ml] = v.y;
            As[k4 * 4 + 2][ml] = v.z;
            As[k4 * 4 + 3][ml] = v.w;
        }
        {
            int gr = tid >> 4;             // 0..15
            int k4 = tid & 15;
            float4 v = *(const float4*)(G + (size_t)gr * 512 + k0 + k4 * 4);
            Gs[gr][k4 * 4 + 0] = v.x;
            Gs[gr][k4 * 4 + 1] = v.y;
            Gs[gr][k4 * 4 + 2] = v.z;
            Gs[gr][k4 * 4 + 3] = v.w;
        }
        __syncthreads();
        #pragma unroll 16
        for (int kk = 0; kk < FB_BK; ++kk) {
            float g = Gs[tx][kk];
            #pragma unroll
            for (int i = 0; i < 8; ++i)
                acc[i] = fmaf(As[kk][ty + 16 * i], g, acc[i]);
        }
    }
    float c = C16[tx];
    #pragma unroll
    for (int i = 0; i < 8; ++i) {
        int gm = m0 + ty + 16 * i;
        if (gm < M) {
            float v = acc[i] + c;
            if (tx < 8) f1[(size_t)gm * 8 + tx] = v;
            else        f2[(size_t)gm * 8 + (tx - 8)] = v;
        }
    }
}

// ---------------------------------------------------------------------------
// CSR build: zero, count, hierarchical scan, fill
// ---------------------------------------------------------------------------
__global__ void zero_k(int* __restrict__ deg, int* __restrict__ fill, int n)
{
    int i = blockIdx.x * blockDim.x + threadIdx.x;
    if (i < n) { deg[i] = 0; fill[i] = 0; }
}

__global__ void count_k(const int* __restrict__ ei, int* __restrict__ deg, int E)
{
    int e = blockIdx.x * blockDim.x + threadIdx.x;
    if (e < E) atomicAdd(&deg[ei[e]], 1);
}

__global__ __launch_bounds__(1024) void bscan_k(const int* __restrict__ deg,
    int* __restrict__ row_ptr, int* __restrict__ bsum, int n)
{
    __shared__ int sh[1024];
    int tid = threadIdx.x;
    int i = blockIdx.x * 1024 + tid;
    int x = (i < n) ? deg[i] : 0;
    sh[tid] = x;
    __syncthreads();
    for (int off = 1; off < 1024; off <<= 1) {
        int v = (tid >= off) ? sh[tid - off] : 0;
        __syncthreads();
        sh[tid] += v;
        __syncthreads();
    }
    if (i < n) row_ptr[i] = sh[tid] - x;    // exclusive within block
    if (tid == 1023) bsum[blockIdx.x] = sh[1023];
}

__global__ void sscan_k(int* __restrict__ bsum, int nb)
{
    if (blockIdx.x == 0 && threadIdx.x == 0) {
        int run = 0;
        for (int b = 0; b < nb; ++b) { int t = bsum[b]; bsum[b] = run; run += t; }
    }
}

__global__ void addoff_k(int* __restrict__ row_ptr, const int* __restrict__ bsum,
                         int n, int Etot)
{
    int i = blockIdx.x * blockDim.x + threadIdx.x;
    if (i < n) row_ptr[i] += bsum[i >> 10];
    if (i == 0) row_ptr[n] = Etot;
}

__global__ void fill_k(const int* __restrict__ ei, const int* __restrict__ row_ptr,
                       int* __restrict__ fill, int* __restrict__ col_s, int E)
{
    int e = blockIdx.x * blockDim.x + threadIdx.x;
    if (e >= E) return;
    int r = ei[e];
    int c = ei[E + e];
    int o = atomicAdd(&fill[r], 1);
    col_s[row_ptr[r] + o] = c;
}

// ---------------------------------------------------------------------------
// Attention: ONE THREAD PER ROW, all 8 heads in registers. col_s read once,
// f2 read as one coalesced 32B gather per edge, attn written [E][8] with
// PLAIN stores (round-9 diagnosis: NT stores evicted attn_e8 from cache and
// made tr_k re-fetch 51MB from HBM — the data is consumed immediately).
// inv_den coalesced [N][8]. tr_k produces the [8][E] layout agg needs.
// ---------------------------------------------------------------------------
__global__ void attn_k(const int* __restrict__ row_ptr, const int* __restrict__ col_s,
                       const float* __restrict__ f1, const float* __restrict__ f2,
                       float* __restrict__ attn_e8, float* __restrict__ inv_den,
                       int n_rows)
{
    int n = blockIdx.x * blockDim.x + threadIdx.x;
    if (n >= n_rows) return;
    int s = row_ptr[n], epos = row_ptr[n + 1];
    floatx4 fa = *(const floatx4*)(f1 + (size_t)n * 8);
    floatx4 fb = *(const floatx4*)(f1 + (size_t)n * 8 + 4);
    float F1[8] = {fa[0], fa[1], fa[2], fa[3], fb[0], fb[1], fb[2], fb[3]};
    float den[8] = {0.f, 0.f, 0.f, 0.f, 0.f, 0.f, 0.f, 0.f};
    for (int p = s; p < epos; ++p) {
        int c = col_s[p];
        floatx4 ga = *(const floatx4*)(f2 + (size_t)c * 8);
        floatx4 gb = *(const floatx4*)(f2 + (size_t)c * 8 + 4);
        float F2[8] = {ga[0], ga[1], ga[2], ga[3], gb[0], gb[1], gb[2], gb[3]};
        float ex[8];
        #pragma unroll
        for (int h = 0; h < 8; ++h) {
            float t = F1[h] + F2[h];
            t = (t > 0.f) ? t : 0.2f * t;   // LeakyReLU
            ex[h] = expf(t);
            den[h] += ex[h];
        }
        floatx4 lo = {ex[0], ex[1], ex[2], ex[3]};
        floatx4 hi = {ex[4], ex[5], ex[6], ex[7]};
        *(floatx4*)(attn_e8 + (size_t)p * 8)     = lo;
        *(floatx4*)(attn_e8 + (size_t)p * 8 + 4) = hi;
    }
    floatx4 iv0, iv1;
    #pragma unroll
    for (int h = 0; h < 4; ++h) iv0[h] = (den[h] > 0.f) ? 1.f / den[h] : 0.f;
    #pragma unroll
    for (int h = 0; h < 4; ++h) iv1[h] = (den[h + 4] > 0.f) ? 1.f / den[h + 4] : 0.f;
    *(floatx4*)(inv_den + (size_t)n * 8)     = iv0;
    *(floatx4*)(inv_den + (size_t)n * 8 + 4) = iv1;
}

// ---------------------------------------------------------------------------
// Transpose [E][8] -> [8][E]. Thread = edge: one 32B coalesced read (mostly
// cache-hits now that attn_k uses plain stores), then per head the wave's 64
// lanes write 64 CONSECUTIVE e-slots = fully-written contiguous lines.
// NT on the output: attn_t is consumed only after L2-flushing GEMMs.
// ---------------------------------------------------------------------------
__global__ void tr_k(const float* __restrict__ in, float* __restrict__ out, int E)
{
    int e = blockIdx.x * blockDim.x + threadIdx.x;
    if (e >= E) return;
    floatx4 a = *(const floatx4*)(in + (size_t)e * 8);
    floatx4 b = *(const floatx4*)(in + (size_t)e * 8 + 4);
    __builtin_nontemporal_store(a[0], out + 0 * (size_t)E + e);
    __builtin_nontemporal_store(a[1], out + 1 * (size_t)E + e);
    __builtin_nontemporal_store(a[2], out + 2 * (size_t)E + e);
    __builtin_nontemporal_store(a[3], out + 3 * (size_t)E + e);
    __builtin_nontemporal_store(b[0], out + 4 * (size_t)E + e);
    __builtin_nontemporal_store(b[1], out + 5 * (size_t)E + e);
    __builtin_nontemporal_store(b[2], out + 6 * (size_t)E + e);
    __builtin_nontemporal_store(b[3], out + 7 * (size_t)E + e);
}

// ---------------------------------------------------------------------------
// fp32 -> fp16 conversion (n multiple of 8)
// ---------------------------------------------------------------------------
__global__ void cvt_f16_k(const float* __restrict__ in, _Float16* __restrict__ out,
                          size_t n)
{
    size_t i = ((size_t)blockIdx.x * blockDim.x + threadIdx.x) * 8;
    if (i >= n) return;
    float4 a = *(const float4*)(in + i);
    float4 b = *(const float4*)(in + i + 4);
    half8 h;
    h[0] = (_Float16)a.x; h[1] = (_Float16)a.y; h[2] = (_Float16)a.z; h[3] = (_Float16)a.w;
    h[4] = (_Float16)b.x; h[5] = (_Float16)b.y; h[6] = (_Float16)b.z; h[7] = (_Float16)b.w;
    *(half8*)(out + i) = h;
}

// ---------------------------------------------------------------------------
// fp16 MFMA GEMM: A[M,K] * B[N,K]^T + bias -> C head-major [N/64][M][64].
// 2D grid dim3(N/TN, M/TM) — blockIdx.x = n-block FASTEST so the 4 n-blocks
// sharing an A-panel are consecutive in dispatch order (r2's best-measured
// config; the r5 nb-loop variant cost ~40-50us/GEMM in tail imbalance with
// only 782 long blocks). 128x128 tile, BK=64, global_load_lds width 16,
// T2 XOR swizzle via pre-swizzled global source. K%64==0, N%128==0.
// ---------------------------------------------------------------------------
#define TM 128
#define TN 128
#define TK 64
__global__ __launch_bounds__(256) void gemm_f16_mfma(
    const _Float16* __restrict__ A,   // [M,K]
    const _Float16* __restrict__ B,   // [N,K]
    const float* __restrict__ bias,   // [N]
    _Float16* __restrict__ C,         // [N/64][M][64] head-major
    int M, int N, int K)
{
    __shared__ _Float16 smem_h[TM * TK + TN * TK];   // 32 KB; reused for epilogue
    _Float16* Ash = smem_h;
    _Float16* Bsh = smem_h + TM * TK;
    int tid = threadIdx.x;
    int wave = tid >> 6;
    int lane = tid & 63;
    int m0 = blockIdx.y * TM;      // y = m-panel
    int n0 = blockIdx.x * TN;      // x = n-block (fastest varying)
    int wm = (wave & 1) * 64;
    int wn = (wave >> 1) * 64;

    floatx4 acc[4][4] = {};

    int fm = lane & 15;
    int q  = lane >> 4;
    int lrow = lane >> 3;                 // 0..7: row within one load instr
    int lcol = (lane & 7) ^ lrow;         // pre-swizzled source col16 slot

    for (int k0 = 0; k0 < K; k0 += TK) {
        __syncthreads();
        #pragma unroll
        for (int t = 0; t < 4; ++t) {
            int r = wave * 8 + t * 32;           // 8 rows per instr, 128 total
            int gr = m0 + r + lrow;
            if (gr > M - 1) gr = M - 1;
            const _Float16* ga = A + (size_t)gr * K + k0 + lcol * 8;
            __builtin_amdgcn_global_load_lds(
                (const __attribute__((address_space(1))) void*)ga,
                (__attribute__((address_space(3))) void*)&Ash[r * TK], 16, 0, 0);
            const _Float16* gb = B + (size_t)(n0 + r + lrow) * K + k0 + lcol * 8;
            __builtin_amdgcn_global_load_lds(
                (const __attribute__((address_space(1))) void*)gb,
                (__attribute__((address_space(3))) void*)&Bsh[r * TK], 16, 0, 0);
        }
        __syncthreads();
        #pragma unroll
        for (int kq = 0; kq < 2; ++kq) {
            half8 af[4], bf[4];
            int sw = ((kq << 2) + q);
            #pragma unroll
            for (int i = 0; i < 4; ++i) {
                int ar = wm + i * 16 + fm;
                af[i] = *(const half8*)&Ash[ar * TK + ((sw ^ (fm & 7)) << 3)];
                int br = wn + i * 16 + fm;
                bf[i] = *(const half8*)&Bsh[br * TK + ((sw ^ (fm & 7)) << 3)];
            }
            #pragma unroll
            for (int i = 0; i < 4; ++i)
                #pragma unroll
                for (int j = 0; j < 4; ++j)
                    acc[i][j] = __builtin_amdgcn_mfma_f32_16x16x32_f16(af[i], bf[j], acc[i][j], 0, 0, 0);
        }
    }
    // Epilogue: per i-subtile (16 rows x 64 cols per wave), stage in LDS with
    // rq-based XOR swizzle, read back coalesced, half8 store.
    // Each wave's 64-col chunk = exactly one head -> head-major store.
    int cn = lane & 15;
    int rq = lane >> 4;               // 0..3
    int head = (n0 + wn) >> 6;
    _Float16* Csh = smem_h + wave * 1024;   // 16*64 halves per wave
    #pragma unroll
    for (int i = 0; i < 4; ++i) {
        __syncthreads();              // protect smem reuse across waves/stages
        #pragma unroll
        for (int j = 0; j < 4; ++j) {
            int col = j * 16 + cn;                  // 0..63
            float bsv = bias[n0 + wn + col];
            int scol = col ^ (rq * 16);             // swizzle: rq picks 16-col block
            #pragma unroll
            for (int r = 0; r < 4; ++r) {
                int row = rq * 4 + r;               // 0..15
                Csh[row * 64 + scol] = (_Float16)(acc[i][j][r] + bsv);
            }
        }
        __syncthreads();
        #pragma unroll
        for (int t = 0; t < 2; ++t) {
            int row = t * 8 + (lane >> 3);          // 0..15
            int c0 = (lane & 7) * 8;                // aligned-8 col run
            int sc0 = c0 ^ (((row >> 2) & 3) * 16); // same swizzle (rq = row>>2)
            half8 v = *(const half8*)&Csh[row * 64 + sc0];
            int gm = m0 + wm + i * 16 + row;
            if (gm < M)
                *(half8*)&C[((size_t)head * M + gm) * 64 + c0] = v;
        }
    }
}

// ---------------------------------------------------------------------------
// fp16 MFMA GEMM, N=64, fp32 out: C[M,64] = A[M,K]*B[64,K]^T + bias
// ---------------------------------------------------------------------------
#define FG_TM 256
#define FG_TK 32
__global__ __launch_bounds__(256) void gemm_f16_n64(
    const _Float16* __restrict__ A,   // [M,K]
    const _Float16* __restrict__ B,   // [64,K]
    const float* __restrict__ bias,   // [64]
    float* __restrict__ C,            // [M,64]
    int M, int K)
{
    __shared__ _Float16 Ash[FG_TM * FG_TK];
    __shared__ _Float16 Bsh[64 * FG_TK];
    int tid = threadIdx.x;
    int wave = tid >> 6;
    int lane = tid & 63;
    int m0 = blockIdx.x * FG_TM;
    int wm = wave * 64;

    floatx4 acc[4][4] = {};
    int fm = lane & 15;
    int q  = lane >> 4;

    for (int k0 = 0; k0 < K; k0 += FG_TK) {
        __syncthreads();
        #pragma unroll
        for (int t = 0; t < 4; ++t) {
            int r = wave * 16 + t * 64;
            int gr = m0 + r + (lane >> 2);
            if (gr > M - 1) gr = M - 1;
            const _Float16* ga = A + (size_t)gr * K + k0 + (lane & 3) * 8;
            __builtin_amdgcn_global_load_lds(
                (const __attribute__((address_space(1))) void*)ga,
                (__attribute__((address_space(3))) void*)&Ash[r * FG_TK], 16, 0, 0);
        }
        {
            int r = wave * 16;
            const _Float16* gb = B + (size_t)(r + (lane >> 2)) * K + k0 + (lane & 3) * 8;
            __builtin_amdgcn_global_load_lds(
                (const __attribute__((address_space(1))) void*)gb,
                (__attribute__((address_space(3))) void*)&Bsh[r * FG_TK], 16, 0, 0);
        }
        __syncthreads();
        half8 af[4], bf[4];
        #pragma unroll
        for (int i = 0; i < 4; ++i) {
            af[i] = *(const half8*)&Ash[(wm + i * 16 + fm) * FG_TK + q * 8];
            bf[i] = *(const half8*)&Bsh[(i * 16 + fm) * FG_TK + q * 8];
        }
        #pragma unroll
        for (int i = 0; i < 4; ++i)
            #pragma unroll
            for (int j = 0; j < 4; ++j)
                acc[i][j] = __builtin_amdgcn_mfma_f32_16x16x32_f16(af[i], bf[j], acc[i][j], 0, 0, 0);
    }
    int cn = lane & 15;
    int rq = lane >> 4;
    #pragma unroll
    for (int i = 0; i < 4; ++i) {
        #pragma unroll
        for (int j = 0; j < 4; ++j) {
            int gn = j * 16 + cn;
            float bsv = bias[gn];
            #pragma unroll
            for (int r = 0; r < 4; ++r) {
                int gm = m0 + wm + i * 16 + rq * 4 + r;
                if (gm < M)
                    C[(size_t)gm * NOUT + gn] = acc[i][j][r] + bsv;
            }
        }
    }
}

// ---------------------------------------------------------------------------
// HEAD-PARTITIONED aggregation (round-8 verified best: 213us, FETCH 679MB;
// round-9's 4-edge unroll raised the delivered rate but thrashed L2 for a
// net zero — structural equilibrium). head = bid%8 -> per-XCD 12.8MB gather
// table. Each 8-lane group owns one (row, head), lane = channel slot
// (8x16B = 128B head-row), channels lane-private, 2-edge unroll.
// ---------------------------------------------------------------------------
__global__ __launch_bounds__(256) void agg_h_k(const int* __restrict__ row_ptr,
    const int* __restrict__ col_s, const float* __restrict__ attn_t,
    const float* __restrict__ inv_den, const _Float16* __restrict__ xw,
    _Float16* __restrict__ out, int n_rows, int E)
{
    int head   = blockIdx.x & 7;
    int rowblk = blockIdx.x >> 3;
    int wave   = threadIdx.x >> 6;
    int lane   = threadIdx.x & 63;
    int row    = rowblk * 32 + wave * 8 + (lane >> 3);
    int cs     = lane & 7;             // channel slot: 8 fp16 = 16B
    const float*    attn_h = attn_t + (size_t)head * E;
    const _Float16* xw_h   = xw + (size_t)head * n_rows * 64;

    bool act = row < n_rows;
    int s = act ? row_ptr[row]     : 0;
    int e = act ? row_ptr[row + 1] : 0;

    float acc0[8] = {0.f, 0.f, 0.f, 0.f, 0.f, 0.f, 0.f, 0.f};
    float acc1[8] = {0.f, 0.f, 0.f, 0.f, 0.f, 0.f, 0.f, 0.f};
    int p = s;
    for (; p + 2 <= e; p += 2) {
        int c0 = col_s[p];
        int c1 = col_s[p + 1];
        float a0 = attn_h[p];
        float a1 = attn_h[p + 1];
        half8 x0 = *(const half8*)(xw_h + (size_t)c0 * 64 + cs * 8);
        half8 x1 = *(const half8*)(xw_h + (size_t)c1 * 64 + cs * 8);
        #pragma unroll
        for (int u = 0; u < 8; ++u) {
            acc0[u] = fmaf(a0, (float)x0[u], acc0[u]);
            acc1[u] = fmaf(a1, (float)x1[u], acc1[u]);
        }
    }
    if (p < e) {
        int c0 = col_s[p];
        float a0 = attn_h[p];
        half8 x0 = *(const half8*)(xw_h + (size_t)c0 * 64 + cs * 8);
        #pragma unroll
        for (int u = 0; u < 8; ++u)
            acc0[u] = fmaf(a0, (float)x0[u], acc0[u]);
    }
    if (!act) return;
    float inv = inv_den[(size_t)row * 8 + head];
    half8 o;
    #pragma unroll
    for (int u = 0; u < 8; ++u) {
        float v = (acc0[u] + acc1[u]) * inv;
        v = (v > 0.f) ? v : (expf(v) - 1.f);   // ELU
        o[u] = (_Float16)v;
    }
    __builtin_nontemporal_store(o,
        (half8*)(out + (size_t)row * HD + head * 64 + cs * 8));
}

// ---------------------------------------------------------------------------
extern "C" void kernel_launch(void* const* d_in, const int* in_sizes, int n_in,
                              void* d_out, int out_size, void* d_ws, size_t ws_size,
                              hipStream_t stream)
{
    const float* feat   = (const float*)d_in[0];
    const int*   ei     = (const int*)  d_in[1];
    const float* fW_w   = (const float*)d_in[2];
    const float* fW_b   = (const float*)d_in[3];
    const float* a_src  = (const float*)d_in[4];
    const float* a_dest = (const float*)d_in[5];
    const float* W0     = (const float*)d_in[6];
    const float* b0     = (const float*)d_in[7];
    const float* W1     = (const float*)d_in[8];
    const float* b1     = (const float*)d_in[9];
    const float* lin_w  = (const float*)d_in[10];
    const float* lin_b  = (const float*)d_in[11];
    float* outp = (float*)d_out;

    const int N = in_sizes[0] / NFEAT;
    const int E = in_sizes[1] / 2;
    const int NB = (N + 1023) / 1024;

    // workspace carve-up (256B aligned)
    char* ws = (char*)d_ws;
    size_t off = 0;
    auto carve = [&](size_t bytes) -> char* {
        char* p = ws + off;
        off += (bytes + 255) & ~(size_t)255;
        return p;
    };
    float*     G       = (float*)carve(16 * 512 * sizeof(float));
    float*     C16     = (float*)carve(16 * sizeof(float));
    float*     f1      = (float*)carve((size_t)N * 8 * sizeof(float));
    float*     f2      = (float*)carve((size_t)N * 8 * sizeof(float));
    int*       deg     = (int*)  carve((size_t)N * sizeof(int));
    int*       fillc   = (int*)  carve((size_t)N * sizeof(int));
    int*       row_ptr = (int*)  carve(((size_t)N + 1) * sizeof(int));
    int*       bsum    = (int*)  carve((size_t)NB * sizeof(int));
    int*       col_s   = (int*)  carve((size_t)E * sizeof(int));
    float*     attn_t  = (float*)carve((size_t)E * 8 * sizeof(float));   // [8][E]
    float*     inv_den = (float*)carve((size_t)N * 8 * sizeof(float));   // [N][8]
    _Float16*  W0h     = (_Float16*)carve((size_t)HD * NFEAT * sizeof(_Float16));
    _Float16*  W1h     = (_Float16*)carve((size_t)HD * HD * sizeof(_Float16));
    _Float16*  linWh   = (_Float16*)carve((size_t)NOUT * HD * sizeof(_Float16));
    _Float16*  hbuf1   = (_Float16*)carve((size_t)N * NFEAT * sizeof(_Float16)); // featH -> x1H -> x2H
    _Float16*  xwH     = (_Float16*)carve((size_t)N * HD * sizeof(_Float16));    // [8][N][64]
    // [E][8] attn scratch ALIASES xwH (dead until first GEMM; 102MB >= 51MB)
    float*     attn_e8 = (float*)xwH;
    (void)ws_size; (void)n_in; (void)out_size;

    // 1. fold a_src/a_dest through fW; f1/f2 per node (+ fused feat->fp16)
    g_k<<<(16 * 512 + 16 + 255) / 256, 256, 0, stream>>>(fW_w, fW_b, a_src, a_dest, G, C16);
    f1f2_k<<<(N + FB_BM - 1) / FB_BM, 256, 0, stream>>>(feat, G, C16, f1, f2, hbuf1, N);
    // 2. CSR build
    zero_k<<<(N + 255) / 256, 256, 0, stream>>>(deg, fillc, N);
    count_k<<<(E + 255) / 256, 256, 0, stream>>>(ei, deg, E);
    bscan_k<<<NB, 1024, 0, stream>>>(deg, row_ptr, bsum, N);
    sscan_k<<<1, 64, 0, stream>>>(bsum, NB);
    addoff_k<<<(N + 255) / 256, 256, 0, stream>>>(row_ptr, bsum, N, E);
    fill_k<<<(E + 255) / 256, 256, 0, stream>>>(ei, row_ptr, fillc, col_s, E);
    // 3. attention: per-row thread, [E][8] (plain stores, cache-resident for
    //    tr_k) + inv [N][8]; transpose to [8][E] for head-partitioned agg.
    attn_k<<<(N + 255) / 256, 256, 0, stream>>>(row_ptr, col_s, f1, f2, attn_e8, inv_den, N);
    tr_k<<<(E + 255) / 256, 256, 0, stream>>>(attn_e8, attn_t, E);

    // 4. weight conversions to fp16
    cvt_f16_k<<<(int)(((size_t)HD * NFEAT / 8 + 255) / 256), 256, 0, stream>>>(W0, W0h, (size_t)HD * NFEAT);
    cvt_f16_k<<<(int)(((size_t)HD * HD / 8 + 255) / 256), 256, 0, stream>>>(W1, W1h, (size_t)HD * HD);
    cvt_f16_k<<<(int)(((size_t)NOUT * HD / 8 + 255) / 256), 256, 0, stream>>>(lin_w, linWh, (size_t)NOUT * HD);

    const int agg_blocks = 8 * ((N + 31) / 32);   // head = bid%8, 32 rows/block

    // 5. layer 0: xw0 = feat @ W0^T + b0 -> xwH (head-major); agg -> hbuf1
    gemm_f16_mfma<<<dim3(HD / TN, (N + TM - 1) / TM), 256, 0, stream>>>(
        hbuf1, W0h, b0, xwH, N, HD, NFEAT);
    agg_h_k<<<agg_blocks, 256, 0, stream>>>(
        row_ptr, col_s, attn_t, inv_den, xwH, hbuf1, N, E);
    // 6. layer 1: xw1 = x1 @ W1^T + b1 -> xwH (head-major); agg -> hbuf1
    gemm_f16_mfma<<<dim3(HD / TN, (N + TM - 1) / TM), 256, 0, stream>>>(
        hbuf1, W1h, b1, xwH, N, HD, HD);
    agg_h_k<<<agg_blocks, 256, 0, stream>>>(
        row_ptr, col_s, attn_t, inv_den, xwH, hbuf1, N, E);
    // 7. final linear (fp16 MFMA, fp32 out) -> d_out
    gemm_f16_n64<<<(N + FG_TM - 1) / FG_TM, 256, 0, stream>>>(
        hbuf1, linWh, lin_b, outp, N, HD);
}